// Round 1
// baseline (1403.875 us; speedup 1.0000x reference)
//
#include <hip/hip_runtime.h>
#include <hip/hip_bf16.h>
#include <stdint.h>

// Problem constants
#define B_SZ   4096
#define F_SZ   40960
#define M_SZ   256
#define KSPLIT 4
#define KSLICE (F_SZ / KSPLIT)   // 10240
#define BK     64
#define NCHUNK (KSLICE / BK)     // 160
#define AROWS  128               // 64 white + 64 black rows per tile
#define WR     256               // all of M
#define LDT    72                // LDS row pitch in bf16 (64 + 8 pad -> 144 B = 9x16B, conflict-free b128)

typedef float    f32x4  __attribute__((ext_vector_type(4)));
typedef __bf16   bf16x4 __attribute__((ext_vector_type(4)));
typedef __bf16   bf16x8 __attribute__((ext_vector_type(8)));
typedef unsigned int u32x4 __attribute__((ext_vector_type(4)));

// ws layout: [0, 20971520): ft_w as bf16 [256][40960]
//            [20971520, 54525952): split-K partials float [KSPLIT][4096][512]
#define WS_WBF_BYTES ((size_t)M_SZ * F_SZ * 2)

// ---------------------------------------------------------------------------
// Kernel 0: ft_w fp32 -> bf16 (once per call; ws is re-poisoned every launch)
// ---------------------------------------------------------------------------
__global__ __launch_bounds__(256) void k_wcvt(const float* __restrict__ src,
                                              __bf16* __restrict__ dst) {
    size_t i = ((size_t)blockIdx.x * 256 + threadIdx.x) * 8;
    f32x4 a = *(const f32x4*)(src + i);
    f32x4 b = *(const f32x4*)(src + i + 4);
    bf16x4 oa = __builtin_convertvector(a, bf16x4);
    bf16x4 ob = __builtin_convertvector(b, bf16x4);
    *(bf16x4*)(dst + i)     = oa;
    *(bf16x4*)(dst + i + 4) = ob;
}

// ---------------------------------------------------------------------------
// Kernel 1: feature-transformer GEMM.
// Tile: 128 A-rows (rows 0-63 = white[r0..r0+63], rows 64-127 = black[r0..])
//       x 256 cols (all of M), K-slice of 10240 per blockIdx.y.
// 512 threads = 8 waves; wave (wv>>2, wv&3) owns a 64x64 subtile (4x4 frags).
// Partials (no ft_b bias) written to part[slice][batch][persp*256+m].
// ---------------------------------------------------------------------------
__global__ __launch_bounds__(512, 2) void k_ftgemm(
    const float* __restrict__ white, const float* __restrict__ black,
    const __bf16* __restrict__ wbf, float* __restrict__ part)
{
    __shared__ __bf16 Abuf[AROWS * LDT];   // 18432 B
    __shared__ __bf16 Wbuf[WR * LDT];      // 36864 B

    const int tid   = threadIdx.x;
    const int r0    = blockIdx.x * 64;
    const int kbase = blockIdx.y * KSLICE;

    // staging-load mapping: thread -> (row rw in 0..63, 16B-column c8 in 0..7)
    const int rw = tid >> 3;
    const int c8 = tid & 7;

    const float*  aW = white + (size_t)(r0 + rw) * F_SZ + kbase + c8 * 8;
    const float*  aB = black + (size_t)(r0 + rw) * F_SZ + kbase + c8 * 8;

    f32x4 areg[4];   // white row (2x float4), black row (2x float4)
    u32x4 wreg[4];   // 4 W rows x 8 bf16 (raw 16B)

    // MFMA mapping
    const int lane = tid & 63;
    const int wv   = tid >> 6;          // 0..7
    const int m0   = (wv & 3) * 64;     // col block
    const int ar0  = (wv >> 2) * 64;    // A-row block (0=white strip, 64=black strip)
    const int lr   = lane & 15;
    const int q    = lane >> 4;

    f32x4 acc[4][4];
#pragma unroll
    for (int r = 0; r < 4; ++r)
#pragma unroll
        for (int c = 0; c < 4; ++c) acc[r][c] = (f32x4){0.f, 0.f, 0.f, 0.f};

    auto load_chunk = [&](int kc) {
        const int ko = kc * BK;
        areg[0] = *(const f32x4*)(aW + ko);
        areg[1] = *(const f32x4*)(aW + ko + 4);
        areg[2] = *(const f32x4*)(aB + ko);
        areg[3] = *(const f32x4*)(aB + ko + 4);
#pragma unroll
        for (int it = 0; it < 4; ++it)
            wreg[it] = *(const u32x4*)(wbf + (size_t)(rw + it * 64) * F_SZ
                                       + kbase + ko + c8 * 8);
    };

    load_chunk(0);

    for (int kc = 0; kc < NCHUNK; ++kc) {
        __syncthreads();   // previous chunk's readers done
        {   // regs -> LDS (A: cvt to bf16; W: raw copy)
            bf16x4 lo = __builtin_convertvector(areg[0], bf16x4);
            bf16x4 hi = __builtin_convertvector(areg[1], bf16x4);
            *(bf16x4*)&Abuf[rw * LDT + c8 * 8]     = lo;
            *(bf16x4*)&Abuf[rw * LDT + c8 * 8 + 4] = hi;
            lo = __builtin_convertvector(areg[2], bf16x4);
            hi = __builtin_convertvector(areg[3], bf16x4);
            *(bf16x4*)&Abuf[(64 + rw) * LDT + c8 * 8]     = lo;
            *(bf16x4*)&Abuf[(64 + rw) * LDT + c8 * 8 + 4] = hi;
#pragma unroll
            for (int it = 0; it < 4; ++it)
                *(u32x4*)&Wbuf[(rw + it * 64) * LDT + c8 * 8] = wreg[it];
        }
        __syncthreads();
        if (kc + 1 < NCHUNK) load_chunk(kc + 1);   // in flight during MFMA

#pragma unroll
        for (int kst = 0; kst < 2; ++kst) {
            bf16x8 af[4], wf[4];
#pragma unroll
            for (int r = 0; r < 4; ++r)
                af[r] = *(const bf16x8*)&Abuf[(ar0 + r * 16 + lr) * LDT + kst * 32 + q * 8];
#pragma unroll
            for (int c = 0; c < 4; ++c)
                wf[c] = *(const bf16x8*)&Wbuf[(m0 + c * 16 + lr) * LDT + kst * 32 + q * 8];
#pragma unroll
            for (int r = 0; r < 4; ++r)
#pragma unroll
                for (int c = 0; c < 4; ++c)
                    acc[r][c] = __builtin_amdgcn_mfma_f32_16x16x32_bf16(
                        af[r], wf[c], acc[r][c], 0, 0, 0);
        }
    }

    // epilogue: C/D layout col=lane&15, row=quad*4+e
    float* pbase = part + (size_t)blockIdx.y * ((size_t)B_SZ * 512);
#pragma unroll
    for (int r = 0; r < 4; ++r) {
        const int arow_base = ar0 + r * 16 + q * 4;
#pragma unroll
        for (int e = 0; e < 4; ++e) {
            const int arow  = arow_base + e;
            const int i     = r0 + (arow & 63);
            const int cbase = (arow >> 6) * 256 + m0;   // persp offset + col block
#pragma unroll
            for (int c = 0; c < 4; ++c)
                pbase[(size_t)i * 512 + cbase + c * 16 + lr] = acc[r][c][e];
        }
    }
}

// ---------------------------------------------------------------------------
// Kernel 2: split-K reduce + bias + clip + stm-select, then l1/l2 head (fp32).
// One wave per batch row; 4 rows per 256-thread block.
// ---------------------------------------------------------------------------
__global__ __launch_bounds__(256) void k_head(
    const float* __restrict__ part, const float* __restrict__ stm,
    const float* __restrict__ ftb,  const float* __restrict__ l1w,
    const float* __restrict__ l1b,  const float* __restrict__ l2w,
    const float* __restrict__ l2b,  float* __restrict__ out)
{
    __shared__ float xs[4][512];
    const int wv   = threadIdx.x >> 6;
    const int lane = threadIdx.x & 63;
    const int i    = blockIdx.x * 4 + wv;

    const int swap = (stm[i] == 0.0f) ? 256 : 0;   // stm==0 -> [b, w]

#pragma unroll
    for (int t = 0; t < 8; ++t) {
        const int j   = t * 64 + lane;
        const int col = (j + swap) & 511;
        float v = 0.f;
#pragma unroll
        for (int s = 0; s < KSPLIT; ++s)
            v += part[(size_t)s * B_SZ * 512 + (size_t)i * 512 + col];
        v += ftb[j & 255];
        v = fminf(fmaxf(v, 0.f), 1.f);
        xs[wv][j] = v;
    }
    __syncthreads();

    // l1: lane = (n in 0..31, h in 0..1); each lane does 256 MACs (float4)
    const int n = lane & 31;
    const int h = lane >> 5;
    float a = 0.f;
    const float* wrow = l1w + n * 512 + h * 256;
    const float* xrow = &xs[wv][h * 256];
#pragma unroll 8
    for (int jj = 0; jj < 256; jj += 4) {
        f32x4 xv = *(const f32x4*)(xrow + jj);
        f32x4 wv4 = *(const f32x4*)(wrow + jj);
        a += xv.x * wv4.x + xv.y * wv4.y + xv.z * wv4.z + xv.w * wv4.w;
    }
    a += __shfl_xor(a, 32);                 // combine halves
    float y = fminf(fmaxf(a + l1b[n], 0.f), 1.f);

    float p = (h == 0) ? y * l2w[n] : 0.f;  // l2 dot over 32 outputs
#pragma unroll
    for (int off = 16; off >= 1; off >>= 1) p += __shfl_xor(p, off);
    if (lane == 0) out[i] = p + l2b[0];
}

// ---------------------------------------------------------------------------
extern "C" void kernel_launch(void* const* d_in, const int* in_sizes, int n_in,
                              void* d_out, int out_size, void* d_ws, size_t ws_size,
                              hipStream_t stream) {
    (void)in_sizes; (void)n_in; (void)out_size; (void)ws_size;
    const float* white = (const float*)d_in[0];
    const float* black = (const float*)d_in[1];
    const float* stm   = (const float*)d_in[2];
    const float* ftw   = (const float*)d_in[3];
    const float* ftb   = (const float*)d_in[4];
    const float* l1w   = (const float*)d_in[5];
    const float* l1b   = (const float*)d_in[6];
    const float* l2w   = (const float*)d_in[7];
    const float* l2b   = (const float*)d_in[8];

    __bf16* wbf = (__bf16*)d_ws;                              // 20.97 MB
    float*  part = (float*)((char*)d_ws + WS_WBF_BYTES);      // 33.55 MB (needs ws >= 54.6 MB)

    hipLaunchKernelGGL(k_wcvt, dim3((M_SZ * F_SZ) / (256 * 8)), dim3(256), 0, stream,
                       ftw, wbf);
    hipLaunchKernelGGL(k_ftgemm, dim3(B_SZ / 64, KSPLIT), dim3(512), 0, stream,
                       white, black, wbf, part);
    hipLaunchKernelGGL(k_head, dim3(B_SZ / 4), dim3(256), 0, stream,
                       part, stm, ftb, l1w, l1b, l2w, l2b, (float*)d_out);
}